// Round 1
// baseline (537.590 us; speedup 1.0000x reference)
//
#include <hip/hip_runtime.h>

#define D 64

// ---------------------------------------------------------------------------
// Kernel 1: scatter-add  agg[dst] += x[src]  over all edges.
// One wave (64 lanes) per edge; lane j handles feature j.
// Handles edge_index stored as either int32 or int64 (detected on device).
// ---------------------------------------------------------------------------
__global__ __launch_bounds__(256) void gin_scatter_kernel(
    const float* __restrict__ x,
    const void* __restrict__ edge_index,
    float* __restrict__ agg,
    int n_edges) {
  __shared__ int s_is64;
  if (threadIdx.x == 0) {
    // int64 little-endian with values < 2^32 => every odd uint32 word is 0.
    // int32 random indices in [0,100000): P(64 odd words all zero) ~ 1e-320.
    const unsigned int* w = (const unsigned int*)edge_index;
    int is64 = 1;
    for (int i = 0; i < 64; ++i) {
      if (w[2 * i + 1] != 0u) { is64 = 0; break; }
    }
    s_is64 = is64;
  }
  __syncthreads();
  const int is64 = s_is64;

  const int lane = threadIdx.x & 63;
  int wave = (int)((blockIdx.x * blockDim.x + threadIdx.x) >> 6);
  const int nwaves = (int)((gridDim.x * blockDim.x) >> 6);

  const int* ei32 = (const int*)edge_index;
  const long long* ei64 = (const long long*)edge_index;

  for (int e = wave; e < n_edges; e += nwaves) {
    int src, dst;
    if (is64) {
      src = (int)ei64[e];
      dst = (int)ei64[n_edges + e];
    } else {
      src = ei32[e];
      dst = ei32[n_edges + e];
    }
    float v = x[(size_t)src * D + lane];
    atomicAdd(&agg[(size_t)dst * D + lane], v);
  }
}

// ---------------------------------------------------------------------------
// Kernel 2: fused per-node MLP.
//   z = (1+eps)*x + agg ;  h = relu(W1 z + b1) ;  out = W2 h + b2
// One wave per node; lane j owns output feature j.
// W1/W2 staged in LDS transposed with +1 pad => conflict-free reads.
// agg_in may alias out (each wave reads its row fully before writing it).
// ---------------------------------------------------------------------------
__global__ __launch_bounds__(256) void gin_mlp_kernel(
    const float* __restrict__ x,
    const float* __restrict__ agg_in,
    const float* __restrict__ eps_p,
    const float* __restrict__ W1, const float* __restrict__ b1,
    const float* __restrict__ W2, const float* __restrict__ b2,
    float* __restrict__ out,
    int n_nodes) {
  __shared__ float w1t[64 * 65];
  __shared__ float w2t[64 * 65];
  for (int t = threadIdx.x; t < 64 * 64; t += blockDim.x) {
    int j = t >> 6;   // output feature (row of W)
    int k = t & 63;   // input feature  (col of W)
    w1t[k * 65 + j] = W1[t];
    w2t[k * 65 + j] = W2[t];
  }
  __syncthreads();

  const int lane = threadIdx.x & 63;
  const float b1v = b1[lane];
  const float b2v = b2[lane];
  const float scale = 1.0f + eps_p[0];

  int wave = (int)((blockIdx.x * blockDim.x + threadIdx.x) >> 6);
  const int nwaves = (int)((gridDim.x * blockDim.x) >> 6);

  for (int n = wave; n < n_nodes; n += nwaves) {
    const size_t base = (size_t)n * D + lane;
    float z = scale * x[base] + agg_in[base];

    float h = b1v;
#pragma unroll
    for (int k = 0; k < 64; ++k) {
      h += w1t[k * 65 + lane] * __shfl(z, k);
    }
    h = fmaxf(h, 0.0f);

    float o = b2v;
#pragma unroll
    for (int k = 0; k < 64; ++k) {
      o += w2t[k * 65 + lane] * __shfl(h, k);
    }
    out[base] = o;
  }
}

extern "C" void kernel_launch(void* const* d_in, const int* in_sizes, int n_in,
                              void* d_out, int out_size, void* d_ws, size_t ws_size,
                              hipStream_t stream) {
  const float* x   = (const float*)d_in[0];
  const void*  ei  = d_in[1];
  const float* eps = (const float*)d_in[2];
  const float* W1  = (const float*)d_in[3];
  const float* b1  = (const float*)d_in[4];
  const float* W2  = (const float*)d_in[5];
  const float* b2  = (const float*)d_in[6];
  float* out = (float*)d_out;

  const int n_nodes = in_sizes[0] / D;
  const int n_edges = in_sizes[1] / 2;

  // Use d_out as the aggregation buffer (same shape/dtype as output).
  hipMemsetAsync(out, 0, (size_t)n_nodes * D * sizeof(float), stream);

  gin_scatter_kernel<<<4096, 256, 0, stream>>>(x, ei, out, n_edges);

  gin_mlp_kernel<<<2048, 256, 0, stream>>>(x, out, eps, W1, b1, W2, b2, out,
                                           n_nodes);
}

// Round 3
// 492.167 us; speedup vs baseline: 1.0923x; 1.0923x over previous
//
#include <hip/hip_runtime.h>

#define D 64

// ---------------------------------------------------------------------------
// edge_index dtype detection (int32 vs int64), done per-block on device.
// int64 little-endian with values < 2^32 => every odd uint32 word is 0.
// int32 random indices in [0,100000): P(64 odd words all zero) ~ 1e-320.
// ---------------------------------------------------------------------------
#define DETECT_IS64(ei)                                        \
  __shared__ int s_is64;                                       \
  if (threadIdx.x == 0) {                                      \
    const unsigned int* w_ = (const unsigned int*)(ei);        \
    int is64_ = 1;                                             \
    for (int i_ = 0; i_ < 64; ++i_) {                          \
      if (w_[2 * i_ + 1] != 0u) { is64_ = 0; break; }          \
    }                                                          \
    s_is64 = is64_;                                            \
  }                                                            \
  __syncthreads();

// ---------------------------------------------------------------------------
// Sort path kernel 1: histogram of dst.
// ---------------------------------------------------------------------------
__global__ __launch_bounds__(256) void gin_hist(
    const void* __restrict__ edge_index, int* __restrict__ counts,
    int n_edges) {
  DETECT_IS64(edge_index);
  const int* ei32 = (const int*)edge_index;
  const long long* ei64 = (const long long*)edge_index;
  const int i = (int)(blockIdx.x * blockDim.x + threadIdx.x);
  const int stride = (int)(gridDim.x * blockDim.x);
  for (int e = i; e < n_edges; e += stride) {
    const int dst = s_is64 ? (int)ei64[n_edges + e] : ei32[n_edges + e];
    atomicAdd(&counts[dst], 1);
  }
}

// ---------------------------------------------------------------------------
// Sort path kernels 2a/2b/2c: exclusive scan of counts[n] -> off[n+1],
// plus a cursor copy cur[n]. 1024 chunks.
// ---------------------------------------------------------------------------
__global__ __launch_bounds__(256) void gin_scan_a(
    const int* __restrict__ counts, int* __restrict__ tsum, int n, int chunk) {
  const int t = (int)(blockIdx.x * blockDim.x + threadIdx.x);
  if (t >= 1024) return;
  const int beg = t * chunk;
  const int end = min(beg + chunk, n);
  int s = 0;
  for (int i = beg; i < end; ++i) s += counts[i];
  tsum[t] = s;
}

__global__ __launch_bounds__(1024) void gin_scan_b(int* __restrict__ tsum) {
  __shared__ int ls[1024];
  const int t = threadIdx.x;
  const int v = tsum[t];
  ls[t] = v;
  __syncthreads();
  for (int o = 1; o < 1024; o <<= 1) {
    const int a = (t >= o) ? ls[t - o] : 0;
    __syncthreads();
    ls[t] += a;
    __syncthreads();
  }
  tsum[t] = ls[t] - v;  // exclusive
}

__global__ __launch_bounds__(256) void gin_scan_c(
    const int* __restrict__ counts, const int* __restrict__ tsum,
    int* __restrict__ off, int* __restrict__ cur, int n, int chunk,
    int n_edges) {
  const int t = (int)(blockIdx.x * blockDim.x + threadIdx.x);
  if (t == 0) off[n] = n_edges;
  if (t >= 1024) return;
  const int beg = t * chunk;
  const int end = min(beg + chunk, n);
  int run = tsum[t];
  for (int i = beg; i < end; ++i) {
    off[i] = run;
    cur[i] = run;
    run += counts[i];
  }
}

// ---------------------------------------------------------------------------
// Sort path kernel 3: place src into dst-sorted order.
// ---------------------------------------------------------------------------
__global__ __launch_bounds__(256) void gin_place(
    const void* __restrict__ edge_index, int* __restrict__ cur,
    int* __restrict__ sorted_src, int n_edges) {
  DETECT_IS64(edge_index);
  const int* ei32 = (const int*)edge_index;
  const long long* ei64 = (const long long*)edge_index;
  const int i = (int)(blockIdx.x * blockDim.x + threadIdx.x);
  const int stride = (int)(gridDim.x * blockDim.x);
  for (int e = i; e < n_edges; e += stride) {
    int src, dst;
    if (s_is64) {
      src = (int)ei64[e];
      dst = (int)ei64[n_edges + e];
    } else {
      src = ei32[e];
      dst = ei32[n_edges + e];
    }
    const int pos = atomicAdd(&cur[dst], 1);
    sorted_src[pos] = src;
  }
}

// ---------------------------------------------------------------------------
// Sort path kernel 4: gather-aggregate. Wave per node, lane = feature.
// sorted_src[e] is wave-uniform -> scalar load. x rows are L3-resident.
// No atomics.
// ---------------------------------------------------------------------------
__global__ __launch_bounds__(256) void gin_gather(
    const float* __restrict__ x, const int* __restrict__ off,
    const int* __restrict__ sorted_src, float* __restrict__ agg,
    int n_nodes) {
  const int lane = threadIdx.x & 63;
  const int wave = (int)((blockIdx.x * blockDim.x + threadIdx.x) >> 6);
  if (wave >= n_nodes) return;
  const int beg = off[wave];
  const int end = off[wave + 1];
  float v = 0.0f;
  for (int e = beg; e < end; ++e) {
    v += x[(size_t)sorted_src[e] * D + lane];
  }
  agg[(size_t)wave * D + lane] = v;
}

// ---------------------------------------------------------------------------
// Fallback scatter (if ws too small): scalar float atomics, wave per edge.
// ---------------------------------------------------------------------------
__global__ __launch_bounds__(256) void gin_scatter_atomic(
    const float* __restrict__ x, const void* __restrict__ edge_index,
    float* __restrict__ agg, int n_edges) {
  DETECT_IS64(edge_index);
  const int* ei32 = (const int*)edge_index;
  const long long* ei64 = (const long long*)edge_index;
  const int lane = threadIdx.x & 63;
  int wave = (int)((blockIdx.x * blockDim.x + threadIdx.x) >> 6);
  const int nwaves = (int)((gridDim.x * blockDim.x) >> 6);
  for (int e = wave; e < n_edges; e += nwaves) {
    int src, dst;
    if (s_is64) {
      src = (int)ei64[e];
      dst = (int)ei64[n_edges + e];
    } else {
      src = ei32[e];
      dst = ei32[n_edges + e];
    }
    atomicAdd(&agg[(size_t)dst * D + lane], x[(size_t)src * D + lane]);
  }
}

// ---------------------------------------------------------------------------
// Fused per-node MLP, thread-per-node, register-resident.
//   z = (1+eps)*x + agg ;  h = relu(W1 z + b1) ;  out = W2 h + b2
// W1/W2 staged in LDS; every lane reads the SAME address (broadcast
// ds_read_b128, conflict-free). z/h in registers, static indexing only.
// agg_in may alias out (each thread reads only its own row before writing).
// ---------------------------------------------------------------------------
__global__ __launch_bounds__(256) void gin_mlp_kernel(
    const float* __restrict__ x,
    const float* __restrict__ agg_in,
    const float* __restrict__ eps_p,
    const float* __restrict__ W1, const float* __restrict__ b1,
    const float* __restrict__ W2, const float* __restrict__ b2,
    float* __restrict__ out,
    int n_nodes) {
  __shared__ float4 w1s[64 * 16];
  __shared__ float4 w2s[64 * 16];
  __shared__ float b1s[64];
  __shared__ float b2s[64];

  for (int t = threadIdx.x; t < 64 * 16; t += blockDim.x) {
    w1s[t] = ((const float4*)W1)[t];
    w2s[t] = ((const float4*)W2)[t];
  }
  if (threadIdx.x < 64) {
    b1s[threadIdx.x] = b1[threadIdx.x];
    b2s[threadIdx.x] = b2[threadIdx.x];
  }
  __syncthreads();

  const int n = (int)(blockIdx.x * blockDim.x + threadIdx.x);
  if (n >= n_nodes) return;

  const float scale = 1.0f + eps_p[0];
  const float4* xr = (const float4*)(x + (size_t)n * D);
  const float4* ar = (const float4*)(agg_in + (size_t)n * D);

  float4 z[16];
#pragma unroll
  for (int q = 0; q < 16; ++q) {
    const float4 xv = xr[q];
    const float4 av = ar[q];
    z[q].x = scale * xv.x + av.x;
    z[q].y = scale * xv.y + av.y;
    z[q].z = scale * xv.z + av.z;
    z[q].w = scale * xv.w + av.w;
  }

  float h[64];
#pragma unroll
  for (int j = 0; j < 64; ++j) {
    float acc = b1s[j];
#pragma unroll
    for (int q = 0; q < 16; ++q) {
      const float4 w = w1s[j * 16 + q];  // broadcast read
      acc += w.x * z[q].x + w.y * z[q].y + w.z * z[q].z + w.w * z[q].w;
    }
    h[j] = fmaxf(acc, 0.0f);
  }

  float4* orow = (float4*)(out + (size_t)n * D);
#pragma unroll
  for (int j4 = 0; j4 < 16; ++j4) {
    float4 o;
#pragma unroll
    for (int c = 0; c < 4; ++c) {
      const int j = 4 * j4 + c;
      float acc = b2s[j];
#pragma unroll
      for (int q = 0; q < 16; ++q) {
        const float4 w = w2s[j * 16 + q];  // broadcast read
        acc += w.x * h[4 * q + 0] + w.y * h[4 * q + 1] +
               w.z * h[4 * q + 2] + w.w * h[4 * q + 3];
      }
      ((float*)&o)[c] = acc;
    }
    orow[j4] = o;
  }
}

extern "C" void kernel_launch(void* const* d_in, const int* in_sizes, int n_in,
                              void* d_out, int out_size, void* d_ws, size_t ws_size,
                              hipStream_t stream) {
  const float* x   = (const float*)d_in[0];
  const void*  ei  = d_in[1];
  const float* eps = (const float*)d_in[2];
  const float* W1  = (const float*)d_in[3];
  const float* b1  = (const float*)d_in[4];
  const float* W2  = (const float*)d_in[5];
  const float* b2  = (const float*)d_in[6];
  float* out = (float*)d_out;

  const int n_nodes = in_sizes[0] / D;
  const int n_edges = in_sizes[1] / 2;

  // Workspace layout (ints): off[n+1] | cur[n] | counts[n] | tsum[1024] | sorted[E]
  const size_t need =
      ((size_t)(n_nodes + 1) + n_nodes + n_nodes + 1024 + n_edges) * 4;

  if (ws_size >= need) {
    int* off    = (int*)d_ws;
    int* cur    = off + (n_nodes + 1);
    int* counts = cur + n_nodes;
    int* tsum   = counts + n_nodes;
    int* sorted = tsum + 1024;

    (void)hipMemsetAsync(counts, 0, (size_t)n_nodes * 4, stream);

    gin_hist<<<4096, 256, 0, stream>>>(ei, counts, n_edges);

    const int chunk = (n_nodes + 1023) / 1024;
    gin_scan_a<<<4, 256, 0, stream>>>(counts, tsum, n_nodes, chunk);
    gin_scan_b<<<1, 1024, 0, stream>>>(tsum);
    gin_scan_c<<<4, 256, 0, stream>>>(counts, tsum, off, cur, n_nodes, chunk,
                                      n_edges);

    gin_place<<<4096, 256, 0, stream>>>(ei, cur, sorted, n_edges);

    // Aggregate into d_out (gather overwrites every row; no memset needed).
    const int gather_blocks = (n_nodes * 64 + 255) / 256;
    gin_gather<<<gather_blocks, 256, 0, stream>>>(x, off, sorted, out,
                                                  n_nodes);
  } else {
    // Fallback: atomic scatter into d_out.
    (void)hipMemsetAsync(out, 0, (size_t)n_nodes * D * sizeof(float), stream);
    gin_scatter_atomic<<<4096, 256, 0, stream>>>(x, ei, out, n_edges);
  }

  const int mlp_blocks = (n_nodes + 255) / 256;
  gin_mlp_kernel<<<mlp_blocks, 256, 0, stream>>>(x, out, eps, W1, b1, W2, b2,
                                                 out, n_nodes);
}

// Round 4
// 426.704 us; speedup vs baseline: 1.2599x; 1.1534x over previous
//
#include <hip/hip_runtime.h>

#define D 64

// ---------------------------------------------------------------------------
// edge_index dtype detection (int32 vs int64), done per-block on device.
// int64 little-endian with values < 2^32 => every odd uint32 word is 0.
// int32 random indices in [0,100000): P(64 odd words all zero) ~ 1e-320.
// ---------------------------------------------------------------------------
#define DETECT_IS64(ei)                                        \
  __shared__ int s_is64;                                       \
  if (threadIdx.x == 0) {                                      \
    const unsigned int* w_ = (const unsigned int*)(ei);        \
    int is64_ = 1;                                             \
    for (int i_ = 0; i_ < 64; ++i_) {                          \
      if (w_[2 * i_ + 1] != 0u) { is64_ = 0; break; }          \
    }                                                          \
    s_is64 = is64_;                                            \
  }                                                            \
  __syncthreads();

// ---------------------------------------------------------------------------
// Sort path kernel 1: histogram of dst.
// ---------------------------------------------------------------------------
__global__ __launch_bounds__(256) void gin_hist(
    const void* __restrict__ edge_index, int* __restrict__ counts,
    int n_edges) {
  DETECT_IS64(edge_index);
  const int* ei32 = (const int*)edge_index;
  const long long* ei64 = (const long long*)edge_index;
  const int i = (int)(blockIdx.x * blockDim.x + threadIdx.x);
  const int stride = (int)(gridDim.x * blockDim.x);
  for (int e = i; e < n_edges; e += stride) {
    const int dst = s_is64 ? (int)ei64[n_edges + e] : ei32[n_edges + e];
    atomicAdd(&counts[dst], 1);
  }
}

// ---------------------------------------------------------------------------
// Sort path kernels 2a/2b/2c: exclusive scan of counts[n] -> off[n+1],
// plus a cursor copy cur[n]. 1024 chunks.
// ---------------------------------------------------------------------------
__global__ __launch_bounds__(256) void gin_scan_a(
    const int* __restrict__ counts, int* __restrict__ tsum, int n, int chunk) {
  const int t = (int)(blockIdx.x * blockDim.x + threadIdx.x);
  if (t >= 1024) return;
  const int beg = t * chunk;
  const int end = min(beg + chunk, n);
  int s = 0;
  for (int i = beg; i < end; ++i) s += counts[i];
  tsum[t] = s;
}

__global__ __launch_bounds__(1024) void gin_scan_b(int* __restrict__ tsum) {
  __shared__ int ls[1024];
  const int t = threadIdx.x;
  const int v = tsum[t];
  ls[t] = v;
  __syncthreads();
  for (int o = 1; o < 1024; o <<= 1) {
    const int a = (t >= o) ? ls[t - o] : 0;
    __syncthreads();
    ls[t] += a;
    __syncthreads();
  }
  tsum[t] = ls[t] - v;  // exclusive
}

__global__ __launch_bounds__(256) void gin_scan_c(
    const int* __restrict__ counts, const int* __restrict__ tsum,
    int* __restrict__ off, int* __restrict__ cur, int n, int chunk,
    int n_edges) {
  const int t = (int)(blockIdx.x * blockDim.x + threadIdx.x);
  if (t == 0) off[n] = n_edges;
  if (t >= 1024) return;
  const int beg = t * chunk;
  const int end = min(beg + chunk, n);
  int run = tsum[t];
  for (int i = beg; i < end; ++i) {
    off[i] = run;
    cur[i] = run;
    run += counts[i];
  }
}

// ---------------------------------------------------------------------------
// Sort path kernel 3: place src into dst-sorted order.
// ---------------------------------------------------------------------------
__global__ __launch_bounds__(256) void gin_place(
    const void* __restrict__ edge_index, int* __restrict__ cur,
    int* __restrict__ sorted_src, int n_edges) {
  DETECT_IS64(edge_index);
  const int* ei32 = (const int*)edge_index;
  const long long* ei64 = (const long long*)edge_index;
  const int i = (int)(blockIdx.x * blockDim.x + threadIdx.x);
  const int stride = (int)(gridDim.x * blockDim.x);
  for (int e = i; e < n_edges; e += stride) {
    int src, dst;
    if (s_is64) {
      src = (int)ei64[e];
      dst = (int)ei64[n_edges + e];
    } else {
      src = ei32[e];
      dst = ei32[n_edges + e];
    }
    const int pos = atomicAdd(&cur[dst], 1);
    sorted_src[pos] = src;
  }
}

// ---------------------------------------------------------------------------
// Sort path kernel 4: gather-aggregate. Wave per node, lane = feature.
// 4-way unrolled with independent accumulators: 4 row-gathers in flight
// per wave (the round-3 profile showed latency-bound: 13% VALU, 15% HBM).
// No atomics.
// ---------------------------------------------------------------------------
__global__ __launch_bounds__(256) void gin_gather(
    const float* __restrict__ x, const int* __restrict__ off,
    const int* __restrict__ sorted_src, float* __restrict__ agg,
    int n_nodes) {
  const int lane = threadIdx.x & 63;
  const int wave = (int)((blockIdx.x * blockDim.x + threadIdx.x) >> 6);
  if (wave >= n_nodes) return;
  const int beg = off[wave];
  const int end = off[wave + 1];

  float a0 = 0.0f, a1 = 0.0f, a2 = 0.0f, a3 = 0.0f;
  int e = beg;
  for (; e + 4 <= end; e += 4) {
    const int s0 = sorted_src[e + 0];
    const int s1 = sorted_src[e + 1];
    const int s2 = sorted_src[e + 2];
    const int s3 = sorted_src[e + 3];
    const float v0 = x[(size_t)s0 * D + lane];
    const float v1 = x[(size_t)s1 * D + lane];
    const float v2 = x[(size_t)s2 * D + lane];
    const float v3 = x[(size_t)s3 * D + lane];
    a0 += v0;
    a1 += v1;
    a2 += v2;
    a3 += v3;
  }
  for (; e < end; ++e) {
    a0 += x[(size_t)sorted_src[e] * D + lane];
  }
  agg[(size_t)wave * D + lane] = (a0 + a1) + (a2 + a3);
}

// ---------------------------------------------------------------------------
// Fallback scatter (if ws too small): scalar float atomics, wave per edge.
// ---------------------------------------------------------------------------
__global__ __launch_bounds__(256) void gin_scatter_atomic(
    const float* __restrict__ x, const void* __restrict__ edge_index,
    float* __restrict__ agg, int n_edges) {
  DETECT_IS64(edge_index);
  const int* ei32 = (const int*)edge_index;
  const long long* ei64 = (const long long*)edge_index;
  const int lane = threadIdx.x & 63;
  int wave = (int)((blockIdx.x * blockDim.x + threadIdx.x) >> 6);
  const int nwaves = (int)((gridDim.x * blockDim.x) >> 6);
  for (int e = wave; e < n_edges; e += nwaves) {
    int src, dst;
    if (s_is64) {
      src = (int)ei64[e];
      dst = (int)ei64[n_edges + e];
    } else {
      src = ei32[e];
      dst = ei32[n_edges + e];
    }
    atomicAdd(&agg[(size_t)dst * D + lane], x[(size_t)src * D + lane]);
  }
}

// ---------------------------------------------------------------------------
// Fused per-node MLP, thread-per-node, register-resident.
//   z = (1+eps)*x + agg ;  h = relu(W1 z + b1) ;  out = W2 h + b2
// W1/W2 staged in LDS; every lane reads the SAME address (broadcast
// ds_read_b128, conflict-free). z/h in registers, static indexing only.
// agg_in may alias out (each thread reads only its own row before writing).
// ---------------------------------------------------------------------------
__global__ __launch_bounds__(256) void gin_mlp_kernel(
    const float* __restrict__ x,
    const float* __restrict__ agg_in,
    const float* __restrict__ eps_p,
    const float* __restrict__ W1, const float* __restrict__ b1,
    const float* __restrict__ W2, const float* __restrict__ b2,
    float* __restrict__ out,
    int n_nodes) {
  __shared__ float4 w1s[64 * 16];
  __shared__ float4 w2s[64 * 16];
  __shared__ float b1s[64];
  __shared__ float b2s[64];

  for (int t = threadIdx.x; t < 64 * 16; t += blockDim.x) {
    w1s[t] = ((const float4*)W1)[t];
    w2s[t] = ((const float4*)W2)[t];
  }
  if (threadIdx.x < 64) {
    b1s[threadIdx.x] = b1[threadIdx.x];
    b2s[threadIdx.x] = b2[threadIdx.x];
  }
  __syncthreads();

  const int n = (int)(blockIdx.x * blockDim.x + threadIdx.x);
  if (n >= n_nodes) return;

  const float scale = 1.0f + eps_p[0];
  const float4* xr = (const float4*)(x + (size_t)n * D);
  const float4* ar = (const float4*)(agg_in + (size_t)n * D);

  float4 z[16];
#pragma unroll
  for (int q = 0; q < 16; ++q) {
    const float4 xv = xr[q];
    const float4 av = ar[q];
    z[q].x = scale * xv.x + av.x;
    z[q].y = scale * xv.y + av.y;
    z[q].z = scale * xv.z + av.z;
    z[q].w = scale * xv.w + av.w;
  }

  float h[64];
#pragma unroll
  for (int j = 0; j < 64; ++j) {
    float acc = b1s[j];
#pragma unroll
    for (int q = 0; q < 16; ++q) {
      const float4 w = w1s[j * 16 + q];  // broadcast read
      acc += w.x * z[q].x + w.y * z[q].y + w.z * z[q].z + w.w * z[q].w;
    }
    h[j] = fmaxf(acc, 0.0f);
  }

  float4* orow = (float4*)(out + (size_t)n * D);
#pragma unroll
  for (int j4 = 0; j4 < 16; ++j4) {
    float4 o;
#pragma unroll
    for (int c = 0; c < 4; ++c) {
      const int j = 4 * j4 + c;
      float acc = b2s[j];
#pragma unroll
      for (int q = 0; q < 16; ++q) {
        const float4 w = w2s[j * 16 + q];  // broadcast read
        acc += w.x * h[4 * q + 0] + w.y * h[4 * q + 1] +
               w.z * h[4 * q + 2] + w.w * h[4 * q + 3];
      }
      ((float*)&o)[c] = acc;
    }
    orow[j4] = o;
  }
}

extern "C" void kernel_launch(void* const* d_in, const int* in_sizes, int n_in,
                              void* d_out, int out_size, void* d_ws, size_t ws_size,
                              hipStream_t stream) {
  const float* x   = (const float*)d_in[0];
  const void*  ei  = d_in[1];
  const float* eps = (const float*)d_in[2];
  const float* W1  = (const float*)d_in[3];
  const float* b1  = (const float*)d_in[4];
  const float* W2  = (const float*)d_in[5];
  const float* b2  = (const float*)d_in[6];
  float* out = (float*)d_out;

  const int n_nodes = in_sizes[0] / D;
  const int n_edges = in_sizes[1] / 2;

  // Workspace layout (ints): off[n+1] | cur[n] | counts[n] | tsum[1024] | sorted[E]
  const size_t need =
      ((size_t)(n_nodes + 1) + n_nodes + n_nodes + 1024 + n_edges) * 4;

  if (ws_size >= need) {
    int* off    = (int*)d_ws;
    int* cur    = off + (n_nodes + 1);
    int* counts = cur + n_nodes;
    int* tsum   = counts + n_nodes;
    int* sorted = tsum + 1024;

    (void)hipMemsetAsync(counts, 0, (size_t)n_nodes * 4, stream);

    gin_hist<<<4096, 256, 0, stream>>>(ei, counts, n_edges);

    const int chunk = (n_nodes + 1023) / 1024;
    gin_scan_a<<<4, 256, 0, stream>>>(counts, tsum, n_nodes, chunk);
    gin_scan_b<<<1, 1024, 0, stream>>>(tsum);
    gin_scan_c<<<4, 256, 0, stream>>>(counts, tsum, off, cur, n_nodes, chunk,
                                      n_edges);

    gin_place<<<4096, 256, 0, stream>>>(ei, cur, sorted, n_edges);

    // Aggregate into d_out (gather overwrites every row; no memset needed).
    const int gather_blocks = (n_nodes * 64 + 255) / 256;
    gin_gather<<<gather_blocks, 256, 0, stream>>>(x, off, sorted, out,
                                                  n_nodes);
  } else {
    // Fallback: atomic scatter into d_out.
    (void)hipMemsetAsync(out, 0, (size_t)n_nodes * D * sizeof(float), stream);
    gin_scatter_atomic<<<4096, 256, 0, stream>>>(x, ei, out, n_edges);
  }

  const int mlp_blocks = (n_nodes + 255) / 256;
  gin_mlp_kernel<<<mlp_blocks, 256, 0, stream>>>(x, out, eps, W1, b1, W2, b2,
                                                 out, n_nodes);
}